// Round 8
// baseline (131.857 us; speedup 1.0000x reference)
//
#include <hip/hip_runtime.h>
#include <stdint.h>

#define BATCH 16
#define CIN   128
#define COUT  128
#define IMG_H 64
#define IMG_W 64
#define HW    4096
#define KTOT  1152          // 9*128
#define XH    66
#define XW    66
#define NCQ   16            // ci groups of 8
#define NSTEPS 18           // 1152/64
#define ASTEP 8192          // A elems per step-tile: 8cq*128co*8e

typedef __attribute__((ext_vector_type(8))) __bf16 bf16x8;
typedef __attribute__((ext_vector_type(4))) float  f32x4;
typedef __attribute__((address_space(1))) const void* gas_p;
typedef __attribute__((address_space(3))) void*       las_p;

static __device__ __forceinline__ unsigned short f2bf(float f) {
  union { float f; uint32_t u; } c; c.f = f;
  uint32_t r = c.u + 0x7fffu + ((c.u >> 16) & 1u);   // RNE
  return (unsigned short)(r >> 16);
}

static __device__ __forceinline__ bf16x8 ldg8(const unsigned short* p) {
  uint4 w = *(const uint4*)p;
  return __builtin_bit_cast(bf16x8, w);
}

static __device__ __forceinline__ void gload_lds16(const unsigned short* g, unsigned short* l) {
  __builtin_amdgcn_global_load_lds((gas_p)g, (las_p)l, 16, 0, 0);
}

// ---- fused prep (unchanged) ----
// blocks [0, 1024): bid = h*16+b : x fp32 NCHW -> bf16 xpad[b][66][16cq][66][8], zero halo
// blocks [1024, 1312): idx = step*16+b : w fp32 -> wt4[b][step18][cq8][co128][e8]
__global__ void prep_fused(const float* __restrict__ x, const float* __restrict__ w,
                           unsigned short* __restrict__ wt4, unsigned short* __restrict__ xpad) {
  const int t = threadIdx.x;
  if (blockIdx.x < BATCH * IMG_H) {
    __shared__ uint32_t tile[64 * 68];              // [wcol][ci2], pad 68 words
    const int b = blockIdx.x & 15;
    const int h = blockIdx.x >> 4;
    const float* xb = x + (size_t)b * CIN * HW + h * IMG_W;
    uint4* xp4 = (uint4*)xpad;

    const int lane16 = t & 15;
    const int g      = t >> 4;
#pragma unroll
    for (int it = 0; it < 4; ++it) {
      const int ci = it * 32 + g * 2;
      const float4 va = *(const float4*)(xb + (size_t)ci * HW + lane16 * 4);
      const float4 vb = *(const float4*)(xb + (size_t)(ci + 1) * HW + lane16 * 4);
      const float av[4] = {va.x, va.y, va.z, va.w};
      const float bv[4] = {vb.x, vb.y, vb.z, vb.w};
#pragma unroll
      for (int cc = 0; cc < 4; ++cc)
        tile[(lane16 * 4 + cc) * 68 + it * 16 + g] =
            (uint32_t)f2bf(av[cc]) | ((uint32_t)f2bf(bv[cc]) << 16);
    }
    __syncthreads();

    const uint32_t rbase = ((uint32_t)b * XH + h + 1) * NCQ;
#pragma unroll
    for (int it = 0; it < 4; ++it) {
      const int o   = it * 256 + t;
      const int cqg = o >> 6;
      const int wc  = o & 63;
      const uint4 v = *(const uint4*)&tile[wc * 68 + cqg * 4];
      xp4[(rbase + cqg) * XW + wc + 1] = v;
    }
    if (t < 32) {
      const int cqg = t & 15;
      const int col = (t >> 4) ? 65 : 0;
      xp4[(rbase + cqg) * XW + col] = make_uint4(0, 0, 0, 0);
    }
    if (h == 0) {
      const uint32_t r0  = (uint32_t)b * XH * NCQ * XW;
      const uint32_t r65 = ((uint32_t)b * XH + 65) * NCQ * XW;
      for (int i = t; i < NCQ * XW; i += 256) {
        xp4[r0 + i]  = make_uint4(0, 0, 0, 0);
        xp4[r65 + i] = make_uint4(0, 0, 0, 0);
      }
    }
  } else {
    const int idx  = blockIdx.x - BATCH * IMG_H;    // = step*16 + b
    const int b    = idx & 15;
    const int step = idx >> 4;
    const int khkw = step >> 1;
    const int cib  = (step & 1) << 6;
    const float* wb = w + (size_t)b * COUT * KTOT;
    unsigned short* dst = wt4 + ((size_t)b * NSTEPS + step) * ASTEP;
#pragma unroll
    for (int i = 0; i < 4; ++i) {
      const int c  = i * 256 + t;
      const int cq = c >> 7;
      const int co = c & 127;
      const int ci0 = cib + cq * 8;
      const float* src = wb + (size_t)co * KTOT + (size_t)ci0 * 9 + khkw;
      uint32_t p[4];
#pragma unroll
      for (int e = 0; e < 4; ++e)
        p[e] = (uint32_t)f2bf(src[(2 * e) * 9]) | ((uint32_t)f2bf(src[(2 * e + 1) * 9]) << 16);
      *(uint4*)&dst[(size_t)c * 8] = make_uint4(p[0], p[1], p[2], p[3]);
    }
  }
}

// ---- main: 128co x 128px (2 out rows) per block, persistent B slab, barrier-free K-loop ----
__global__ __launch_bounds__(256, 2) void dynconv_gemm(
    const unsigned short* __restrict__ wt4,   // [B][18][8][128][8] bf16
    const unsigned short* __restrict__ xpad,  // [B][66][16][66][8] bf16, halo=0
    float* __restrict__ out) {                // [B][COUT][64][64] fp32
  __shared__ alignas(16) unsigned short slab[4 * NCQ * 64 * 8];  // 64 KB: [r4][cq16][col64][8]

  const int t    = threadIdx.x;
  const int b    = blockIdx.y;
  const int oh0  = blockIdx.x * 2;            // two output rows per block

  const int lane = t & 63;
  const int wave = t >> 6;
  const int wm   = (wave & 1) << 6;           // co offset (0/64)
  const int osub = wave >> 1;                 // output row sub (0/1)
  const int l15  = lane & 15;
  const int quad = lane >> 4;

  // ---- load B slab: xpad rows oh0..oh0+3, cols 1..64, all 16 cq groups ----
  {
    const unsigned short* xsrc = xpad +
        ((((size_t)b * XH + oh0) * NCQ) * XW + 1 + lane) * 8;
#pragma unroll
    for (int p = 0; p < 16; ++p) {
      const int seg = p * 4 + wave;
      gload_lds16(xsrc + (size_t)seg * XW * 8, &slab[(p * 256 + wave * 64) * 8]);
    }
  }
  __syncthreads();

  // A fragment base: within step tile [cq8][co128][e8], lane reads
  // cq_local = ks*4 + quad, co = wm + i*16 + l15  ->  (quad*128 + wm + l15) here,
  // + ks*512 + i*16 inside LOADA.   (R7 bug: had quad*4*128)
  const unsigned short* wbase = wt4 + (size_t)b * NSTEPS * ASTEP + (size_t)(quad * 128 + wm + l15) * 8;

  f32x4 acc[4][4] = {};
  bf16x8 afA[8], afB[8];

#define LOADA(S, AF)                                                          \
  {                                                                           \
    const unsigned short* wstep_ = wbase + (size_t)(S) * ASTEP;               \
    _Pragma("unroll") for (int ks_ = 0; ks_ < 2; ++ks_)                       \
      _Pragma("unroll") for (int i_ = 0; i_ < 4; ++i_)                        \
        AF[ks_ * 4 + i_] = ldg8(wstep_ + (ks_ * 512 + i_ * 16) * 8);          \
  }

#define COMPUTE(S, AF)                                                        \
  {                                                                           \
    const int khkw_ = (S) >> 1;                                               \
    const int kh_ = khkw_ / 3, kw_ = khkw_ % 3;                               \
    _Pragma("unroll") for (int ks_ = 0; ks_ < 2; ++ks_) {                     \
      const int cq_ = ((S) & 1) * 8 + ks_ * 4 + quad;                         \
      const int rb_ = ((osub + kh_) * NCQ + cq_) * 64;                        \
      bf16x8 bf[4];                                                           \
      _Pragma("unroll") for (int j_ = 0; j_ < 4; ++j_) {                      \
        int cm_ = j_ * 16 + l15 + kw_ - 1;                                    \
        if (j_ == 0) cm_ = cm_ < 0 ? 0 : cm_;                                 \
        if (j_ == 3) cm_ = cm_ > 63 ? 63 : cm_;                               \
        bf[j_] = *(const bf16x8*)&slab[(rb_ + cm_) * 8];                      \
      }                                                                       \
      if (kw_ == 0 && l15 == 0)  bf[0] = (bf16x8){};                          \
      if (kw_ == 2 && l15 == 15) bf[3] = (bf16x8){};                          \
      _Pragma("unroll") for (int i_ = 0; i_ < 4; ++i_)                        \
        _Pragma("unroll") for (int j_ = 0; j_ < 4; ++j_)                      \
          acc[i_][j_] = __builtin_amdgcn_mfma_f32_16x16x32_bf16(              \
              AF[ks_ * 4 + i_], bf[j_], acc[i_][j_], 0, 0, 0);                \
    }                                                                         \
  }

  LOADA(0, afA);
#pragma unroll
  for (int s = 0; s < NSTEPS; s += 2) {
    LOADA(s + 1, afB);
    COMPUTE(s, afA);
    if (s + 2 < NSTEPS) LOADA(s + 2, afA);
    COMPUTE(s + 1, afB);
  }
#undef LOADA
#undef COMPUTE

  // epilogue: co = wm + i*16 + quad*4 + r; pixel row oh0+osub, col = j*16+l15
  float* obase = out + (size_t)b * COUT * HW + (oh0 + osub) * 64;
#pragma unroll
  for (int i = 0; i < 4; ++i) {
#pragma unroll
    for (int r = 0; r < 4; ++r) {
      float* orow = obase + (size_t)(wm + i * 16 + quad * 4 + r) * HW;
#pragma unroll
      for (int j = 0; j < 4; ++j)
        orow[j * 16 + l15] = acc[i][j][r];
    }
  }
}

// ---- safety net: direct fp32 conv ----
__global__ void dynconv_naive(const float* __restrict__ x, const float* __restrict__ w,
                              float* __restrict__ out) {
  const int o   = blockIdx.x * 256 + threadIdx.x;
  const int pix = o & (HW - 1);
  const int co  = (o >> 12) & (COUT - 1);
  const int b   = o >> 19;
  const int oh  = pix >> 6, ow = pix & 63;
  const float* xb = x + (size_t)b * CIN * HW;
  const float* wb = w + ((size_t)b * COUT + co) * CIN * 9;
  float s = 0.f;
  for (int ci = 0; ci < CIN; ++ci) {
    const float* xc = xb + ci * HW;
    const float* wc = wb + ci * 9;
#pragma unroll
    for (int kh = 0; kh < 3; ++kh) {
      const int ih = oh + kh - 1;
      if ((unsigned)ih >= IMG_H) continue;
#pragma unroll
      for (int kw = 0; kw < 3; ++kw) {
        const int iw = ow + kw - 1;
        if ((unsigned)iw >= IMG_W) continue;
        s += xc[ih * IMG_W + iw] * wc[kh * 3 + kw];
      }
    }
  }
  out[o] = s;
}

extern "C" void kernel_launch(void* const* d_in, const int* in_sizes, int n_in,
                              void* d_out, int out_size, void* d_ws, size_t ws_size,
                              hipStream_t stream) {
  const float* x = (const float*)d_in[0];
  const float* w = (const float*)d_in[1];
  float* out = (float*)d_out;

  const size_t wt_bytes = (size_t)BATCH * NSTEPS * ASTEP * sizeof(unsigned short);       //  4.72 MB
  const size_t xp_bytes = (size_t)BATCH * XH * NCQ * XW * 8 * sizeof(unsigned short);    // 17.84 MB

  if (ws_size >= wt_bytes + xp_bytes) {
    unsigned short* wt4  = (unsigned short*)d_ws;
    unsigned short* xpad = (unsigned short*)((char*)d_ws + wt_bytes);
    prep_fused<<<BATCH * IMG_H + BATCH * NSTEPS, 256, 0, stream>>>(x, w, wt4, xpad);
    dim3 grid(IMG_H / 2, BATCH);
    dynconv_gemm<<<grid, 256, 0, stream>>>(wt4, xpad, out);
  } else {
    dynconv_naive<<<(BATCH * COUT * HW) / 256, 256, 0, stream>>>(x, w, out);
  }
}

// Round 9
// 128.022 us; speedup vs baseline: 1.0300x; 1.0300x over previous
//
#include <hip/hip_runtime.h>
#include <stdint.h>

#define BATCH 16
#define CIN   128
#define COUT  128
#define IMG_H 64
#define IMG_W 64
#define HW    4096
#define KTOT  1152          // 9*128
#define XH    66
#define XW    66
#define NCQ   16            // ci groups of 8
#define NST32 36            // K steps of 32 (=4 cq groups)
#define ATILE 4096          // A elems per 32-k step: 4cq*128co*8e (8 KB)

typedef __attribute__((ext_vector_type(8))) __bf16 bf16x8;
typedef __attribute__((ext_vector_type(4))) float  f32x4;
typedef __attribute__((address_space(1))) const void* gas_p;
typedef __attribute__((address_space(3))) void*       las_p;

static __device__ __forceinline__ unsigned short f2bf(float f) {
  union { float f; uint32_t u; } c; c.f = f;
  uint32_t r = c.u + 0x7fffu + ((c.u >> 16) & 1u);   // RNE
  return (unsigned short)(r >> 16);
}

static __device__ __forceinline__ void gload_lds16(const unsigned short* g, unsigned short* l) {
  __builtin_amdgcn_global_load_lds((gas_p)g, (las_p)l, 16, 0, 0);
}

// ---- fused prep (unchanged; wt4 linear layout [b][18][8cq][128][8] == [b][36][4cq][128][8]) ----
__global__ void prep_fused(const float* __restrict__ x, const float* __restrict__ w,
                           unsigned short* __restrict__ wt4, unsigned short* __restrict__ xpad) {
  const int t = threadIdx.x;
  if (blockIdx.x < BATCH * IMG_H) {
    __shared__ uint32_t tile[64 * 68];              // [wcol][ci2], pad 68 words
    const int b = blockIdx.x & 15;
    const int h = blockIdx.x >> 4;
    const float* xb = x + (size_t)b * CIN * HW + h * IMG_W;
    uint4* xp4 = (uint4*)xpad;

    const int lane16 = t & 15;
    const int g      = t >> 4;
#pragma unroll
    for (int it = 0; it < 4; ++it) {
      const int ci = it * 32 + g * 2;
      const float4 va = *(const float4*)(xb + (size_t)ci * HW + lane16 * 4);
      const float4 vb = *(const float4*)(xb + (size_t)(ci + 1) * HW + lane16 * 4);
      const float av[4] = {va.x, va.y, va.z, va.w};
      const float bv[4] = {vb.x, vb.y, vb.z, vb.w};
#pragma unroll
      for (int cc = 0; cc < 4; ++cc)
        tile[(lane16 * 4 + cc) * 68 + it * 16 + g] =
            (uint32_t)f2bf(av[cc]) | ((uint32_t)f2bf(bv[cc]) << 16);
    }
    __syncthreads();

    const uint32_t rbase = ((uint32_t)b * XH + h + 1) * NCQ;
#pragma unroll
    for (int it = 0; it < 4; ++it) {
      const int o   = it * 256 + t;
      const int cqg = o >> 6;
      const int wc  = o & 63;
      const uint4 v = *(const uint4*)&tile[wc * 68 + cqg * 4];
      xp4[(rbase + cqg) * XW + wc + 1] = v;
    }
    if (t < 32) {
      const int cqg = t & 15;
      const int col = (t >> 4) ? 65 : 0;
      xp4[(rbase + cqg) * XW + col] = make_uint4(0, 0, 0, 0);
    }
    if (h == 0) {
      const uint32_t r0  = (uint32_t)b * XH * NCQ * XW;
      const uint32_t r65 = ((uint32_t)b * XH + 65) * NCQ * XW;
      for (int i = t; i < NCQ * XW; i += 256) {
        xp4[r0 + i]  = make_uint4(0, 0, 0, 0);
        xp4[r65 + i] = make_uint4(0, 0, 0, 0);
      }
    }
  } else {
    const int idx  = blockIdx.x - BATCH * IMG_H;    // = step18*16 + b
    const int b    = idx & 15;
    const int step = idx >> 4;
    const int khkw = step >> 1;
    const int cib  = (step & 1) << 6;
    const float* wb = w + (size_t)b * COUT * KTOT;
    unsigned short* dst = wt4 + ((size_t)b * 18 + step) * 8192;
#pragma unroll
    for (int i = 0; i < 4; ++i) {
      const int c  = i * 256 + t;
      const int cq = c >> 7;
      const int co = c & 127;
      const int ci0 = cib + cq * 8;
      const float* src = wb + (size_t)co * KTOT + (size_t)ci0 * 9 + khkw;
      uint32_t p[4];
#pragma unroll
      for (int e = 0; e < 4; ++e)
        p[e] = (uint32_t)f2bf(src[(2 * e) * 9]) | ((uint32_t)f2bf(src[(2 * e + 1) * 9]) << 16);
      *(uint4*)&dst[(size_t)c * 8] = make_uint4(p[0], p[1], p[2], p[3]);
    }
  }
}

// ---- main: 128co x 128px per block, persistent B slab + A LDS double-buffer, 1 barrier/step ----
__global__ __launch_bounds__(256, 2) void dynconv_gemm(
    const unsigned short* __restrict__ wt4,   // [B][36][4cq][128co][8e] bf16
    const unsigned short* __restrict__ xpad,  // [B][66][16][66][8] bf16, halo=0
    float* __restrict__ out) {                // [B][COUT][64][64] fp32
  __shared__ alignas(16) unsigned short slab[4 * NCQ * 64 * 8];   // 64 KB [r4][cq16][col64][8]
  __shared__ alignas(16) unsigned short Abuf[2][ATILE];           // 2 x 8 KB [cq4][co128][8]

  const int t    = threadIdx.x;
  const int b    = blockIdx.y;
  const int oh0  = blockIdx.x * 2;            // two output rows per block

  const int lane = t & 63;
  const int wave = t >> 6;
  const int wm   = (wave & 1) << 6;           // co offset (0/64)
  const int osub = wave >> 1;                 // output row sub (0/1)
  const int l15  = lane & 15;
  const int quad = lane >> 4;

  // ---- B slab: xpad rows oh0..oh0+3, cols 1..64, all 16 cq groups (R8, proven) ----
  {
    const unsigned short* xsrc = xpad +
        ((((size_t)b * XH + oh0) * NCQ) * XW + 1 + lane) * 8;
#pragma unroll
    for (int p = 0; p < 16; ++p) {
      const int seg = p * 4 + wave;           // r = seg>>4, cq = seg&15
      gload_lds16(xsrc + (size_t)seg * XW * 8, &slab[(p * 256 + wave * 64) * 8]);
    }
  }

  const unsigned short* wbase = wt4 + (size_t)b * NST32 * ATILE + (size_t)t * 8;

  // stage A tile for step S into Abuf[BUF]: 512 chunks of 16B, thread does p=0,1
#define STAGEA(S, BUF)                                                        \
  {                                                                           \
    const unsigned short* src_ = wbase + (size_t)(S) * ATILE;                 \
    gload_lds16(src_,        &Abuf[BUF][(wave * 64) * 8]);                    \
    gload_lds16(src_ + 2048, &Abuf[BUF][(256 + wave * 64) * 8]);              \
  }

  STAGEA(0, 0);
  __syncthreads();

  f32x4 acc[4][4] = {};

  for (int s = 0; s < NST32; ++s) {
    if (s + 1 < NST32) STAGEA(s + 1, (s + 1) & 1);

    const int khkw = s >> 2;
    const int kh   = (khkw * 11) >> 5;        // khkw/3
    const int kw   = khkw - kh * 3;
    const int cq_g = ((s & 3) << 2) + quad;   // global ci-group for this lane's k-quad
    const int rb   = ((osub + kh) * NCQ + cq_g) * 64;
    const unsigned short* ab = &Abuf[s & 1][(quad * 128 + wm + l15) * 8];

    bf16x8 af[4], bf[4];
#pragma unroll
    for (int i = 0; i < 4; ++i) af[i] = *(const bf16x8*)(ab + i * 16 * 8);
#pragma unroll
    for (int j = 0; j < 4; ++j) {
      int cm = j * 16 + l15 + kw - 1;
      if (j == 0) cm = cm < 0 ? 0 : cm;
      if (j == 3) cm = cm > 63 ? 63 : cm;
      bf[j] = *(const bf16x8*)&slab[(rb + cm) * 8];
    }
    if (kw == 0 && l15 == 0)  bf[0] = (bf16x8){};
    if (kw == 2 && l15 == 15) bf[3] = (bf16x8){};

#pragma unroll
    for (int i = 0; i < 4; ++i)
#pragma unroll
      for (int j = 0; j < 4; ++j)
        acc[i][j] = __builtin_amdgcn_mfma_f32_16x16x32_bf16(af[i], bf[j], acc[i][j], 0, 0, 0);

    __syncthreads();
  }
#undef STAGEA

  // epilogue: co = wm + i*16 + quad*4 + r; pixel row oh0+osub, col = j*16+l15 (R8, proven)
  float* obase = out + (size_t)b * COUT * HW + (oh0 + osub) * 64;
#pragma unroll
  for (int i = 0; i < 4; ++i) {
#pragma unroll
    for (int r = 0; r < 4; ++r) {
      float* orow = obase + (size_t)(wm + i * 16 + quad * 4 + r) * HW;
#pragma unroll
      for (int j = 0; j < 4; ++j)
        orow[j * 16 + l15] = acc[i][j][r];
    }
  }
}

// ---- safety net: direct fp32 conv ----
__global__ void dynconv_naive(const float* __restrict__ x, const float* __restrict__ w,
                              float* __restrict__ out) {
  const int o   = blockIdx.x * 256 + threadIdx.x;
  const int pix = o & (HW - 1);
  const int co  = (o >> 12) & (COUT - 1);
  const int b   = o >> 19;
  const int oh  = pix >> 6, ow = pix & 63;
  const float* xb = x + (size_t)b * CIN * HW;
  const float* wb = w + ((size_t)b * COUT + co) * CIN * 9;
  float s = 0.f;
  for (int ci = 0; ci < CIN; ++ci) {
    const float* xc = xb + ci * HW;
    const float* wc = wb + ci * 9;
#pragma unroll
    for (int kh = 0; kh < 3; ++kh) {
      const int ih = oh + kh - 1;
      if ((unsigned)ih >= IMG_H) continue;
#pragma unroll
      for (int kw = 0; kw < 3; ++kw) {
        const int iw = ow + kw - 1;
        if ((unsigned)iw >= IMG_W) continue;
        s += xc[ih * IMG_W + iw] * wc[kh * 3 + kw];
      }
    }
  }
  out[o] = s;
}

extern "C" void kernel_launch(void* const* d_in, const int* in_sizes, int n_in,
                              void* d_out, int out_size, void* d_ws, size_t ws_size,
                              hipStream_t stream) {
  const float* x = (const float*)d_in[0];
  const float* w = (const float*)d_in[1];
  float* out = (float*)d_out;

  const size_t wt_bytes = (size_t)BATCH * NST32 * ATILE * sizeof(unsigned short);        //  4.72 MB
  const size_t xp_bytes = (size_t)BATCH * XH * NCQ * XW * 8 * sizeof(unsigned short);    // 17.84 MB

  if (ws_size >= wt_bytes + xp_bytes) {
    unsigned short* wt4  = (unsigned short*)d_ws;
    unsigned short* xpad = (unsigned short*)((char*)d_ws + wt_bytes);
    prep_fused<<<BATCH * IMG_H + BATCH * 18, 256, 0, stream>>>(x, w, wt4, xpad);
    dim3 grid(IMG_H / 2, BATCH);
    dynconv_gemm<<<grid, 256, 0, stream>>>(wt4, xpad, out);
  } else {
    dynconv_naive<<<(BATCH * COUT * HW) / 256, 256, 0, stream>>>(x, w, out);
  }
}